// Round 2
// baseline (395.586 us; speedup 1.0000x reference)
//
#include <hip/hip_runtime.h>
#include <hip/hip_fp16.h>

// CTC-like forward scan. R13 = R12 parallelized across 4 waves (systolic).
//   G_t[p] = G_{t-1}[p] + W_t[p] * G_{t-1}[p-1],  W = exp(x_i - x_4)
// R12 diagnosis: single wave per CU = 1 VALU issue per 2 cycles; 50 VALU
// instrs/step -> 128 cyc/step, 3 of 4 SIMDs idle. Here wave w (of 4) owns
// positions [128w+1, 128w+128] (2 regs/lane), runs time-skewed by 16 steps
// per wave. Boundary G_t[128w] passes wave->wave through a 32-slot LDS ring
// as (mantissa f32, frame i32), written per-step by lane 63, read as a
// 64B burst ONE WINDOW AHEAD (skew-16 + d=8 barriers => producer finished
// those slots last phase; LDS latency hides under a full window).
// Section 0 of the ring is prefilled with (1.0, 0) = the constant G[0]=1,
// so all waves run identical branchless code. Barriers are raw s_barrier +
// lgkmcnt(0) only (no vmcnt drain -> wave0's 4-chunk-ahead global_load_lds
// staging stays in flight). Renorm every 8 steps, down-only alignment
// (lane0 squashes against max imported frame => ldexp shift always <= 0),
// boundary within wave via one v_mov_dpp wave_shr:1. Numerics = R12 scheme.

#define TT 4096
#define BB 64
#define PP 512
#define LN2F 0.69314718055994531f

typedef _Float16 half2_t __attribute__((ext_vector_type(2)));

__device__ __forceinline__ unsigned f16_bits(float f) {
    return (unsigned)__half_as_ushort(__float2half(f));   // v_cvt_f16_f32, RNE
}

// prepass: x[t][b][5] -> xq[t*64+b] = {f16W0|f16W1, f16W2|f16W3, f32 x4, 0}
__global__ __launch_bounds__(256, 1)
void ctc_prepass(const float* __restrict__ x, uint4* __restrict__ xq) {
    int j = blockIdx.x * 256 + threadIdx.x;        // j = t*64 + b
    const float* r = x + (size_t)j * 5;
    float x0 = r[0], x1 = r[1], x2 = r[2], x3 = r[3], x4 = r[4];
    float w0 = fminf(__expf(x0 - x4), 65000.0f);
    float w1 = fminf(__expf(x1 - x4), 65000.0f);
    float w2 = fminf(__expf(x2 - x4), 65000.0f);
    float w3 = fminf(__expf(x3 - x4), 65000.0f);
    uint4 o;
    o.x = f16_bits(w0) | (f16_bits(w1) << 16);
    o.y = f16_bits(w2) | (f16_bits(w3) << 16);
    o.z = __float_as_uint(x4);
    o.w = 0u;
    xq[j] = o;
}

__device__ __forceinline__ void gload_lds16(const void* g, void* l) {
    auto gp = (const __attribute__((address_space(1))) void*)(uintptr_t)g;
    auto lp = (__attribute__((address_space(3))) void*)(uintptr_t)l;
    __builtin_amdgcn_global_load_lds(gp, lp, 16, 0, 0);
}

// lane n <- lane n-1 across the whole wave; lane 0 keeps old (overridden).
__device__ __forceinline__ int shl1w_i(int s) {
    return __builtin_amdgcn_update_dpp(s, s, 0x138 /*wave_shr:1*/, 0xF, 0xF, false);
}
__device__ __forceinline__ float shl1w_f(float s) {
    return __int_as_float(shl1w_i(__float_as_int(s)));
}

__device__ __forceinline__ unsigned comp4(uint4 v, int k) {  // k literal after unroll
    return k == 0 ? v.x : k == 1 ? v.y : k == 2 ? v.z : v.w;
}
__device__ __forceinline__ int imax(int a, int b) { return a > b ? a : b; }

__global__ __launch_bounds__(256, 1)
void ctc_scan(const uint4* __restrict__ xq, const int* __restrict__ seqs,
              const int* __restrict__ seqlens, float* __restrict__ out) {
    __shared__ __align__(16) uint4 ring[512];      // 8 KB: 8 chunks x 64 rows
    __shared__ float garr[PP + 1];
    __shared__ __align__(16) float vsecs[5][32];   // boundary mantissas
    __shared__ __align__(16) int   msecs[5][32];   // boundary frames

    const int b = blockIdx.x;
    const int tid = threadIdx.x;
    const int w = tid >> 6;                        // wave 0..3
    const int l = tid & 63;
    const bool lane0 = (l == 0);
    const bool lane63 = (l == 63);

    // v_perm ctrl: lane l owns positions 128w+2l+1, 128w+2l+2
    // (seq indices 128w+2l, 128w+2l+1)
    unsigned i0 = (unsigned)seqs[b * PP + 128 * w + 2 * l];
    unsigned i1 = (unsigned)seqs[b * PP + 128 * w + 2 * l + 1];
    const unsigned ctrl =
        (2 * i0) | ((2 * i0 + 1) << 8) | ((2 * i1) << 16) | ((2 * i1 + 1) << 24);

    // boundary rings init: section 0 = (1.0, 0) constant (G[0]=1, frame 0);
    // sections 1..4 = (0, 0) (G_{t<0} = 0).
    if (tid < 160) {
        (&vsecs[0][0])[tid] = (tid < 32) ? 1.0f : 0.0f;
        (&msecs[0][0])[tid] = 0;
    }

    const uint4* gsrc = xq + b;                    // row (t,b) at xq[t*64+b]
    if (w == 0) {
#pragma unroll
        for (int c0 = 0; c0 < 4; ++c0)
            gload_lds16(gsrc + (size_t)(c0 * 64 + l) * 64, &ring[c0 * 64 + l]);
    }
    __syncthreads();   // ring init visible; wave0 vmcnt drained -> chunks 0..3 resident

    float F[2] = {0.0f, 0.0f};                     // G values, frame 2^M
    int M = 0;
    float logs = 0.0f;                             // sum x_4 over processed t
    int t0 = -16 * w;                              // time base of next window

    float* const vexp = &vsecs[w + 1][0];
    int*   const mexp = &msecs[w + 1][0];
    const float* const vimp = &vsecs[w][0];
    const int*   const mimp = &msecs[w][0];

    uint4 wA[8], wB[8];                            // row windows
    uint4 iA[4], iB[4];                            // import windows {v0..7, M0..7}
#pragma unroll
    for (int i = 0; i < 8; ++i) wA[i] = ring[i];   // rows 0..7
    {
        const int s0 = t0 & 31;
        const uint4* vq = (const uint4*)(vimp + s0);
        const uint4* mq = (const uint4*)(mimp + s0);
        iA[0] = vq[0]; iA[1] = vq[1]; iA[2] = mq[0]; iA[3] = mq[1];
    }

    auto phase = [&](uint4 (&cur)[8], uint4 (&nxt)[8],
                     uint4 (&icur)[4], uint4 (&inxt)[4]) {
        // ---- prefetch rows + imports for NEXT window (always; garbage-safe
        //      when inactive, keeps A/B parity static) ----
        const int rb = (t0 + 8) & 511;
        const int s0n = (t0 + 8) & 31;
#pragma unroll
        for (int i = 0; i < 8; ++i) nxt[i] = ring[rb + i];
        {
            const uint4* vq = (const uint4*)(vimp + s0n);
            const uint4* mq = (const uint4*)(mimp + s0n);
            inxt[0] = vq[0]; inxt[1] = vq[1]; inxt[2] = mq[0]; inxt[3] = mq[1];
        }
        asm volatile("" ::: "memory");

        if (t0 >= 0 && t0 < TT) {                  // wave-uniform activity
            // ---- bookkeeping: renorm + frame alignment ----
            const int mi = imax(imax(imax((int)icur[2].x, (int)icur[2].y),
                                     imax((int)icur[2].z, (int)icur[2].w)),
                                imax(imax((int)icur[3].x, (int)icur[3].y),
                                     imax((int)icur[3].z, (int)icur[3].w)));
            float m = fmaxf(F[0], F[1]);
            int e2 = ((__float_as_int(m) >> 23) & 0xFF) - 127;
            e2 = (m > 0.0f) ? e2 : 0;
            const int Mp = M + e2;
            const int Mlp = shl1w_i(Mp);
            const int left = lane0 ? mi : Mlp;     // lane0: max imported frame
            int dl = left - Mp;
            int dlc = dl > 0 ? dl : 0;             // down-only self-squash
            const int Mnew = Mp + dlc;
            const int sh = Mnew - M;               // >= 0
            F[0] = ldexpf(F[0], -sh);
            F[1] = ldexpf(F[1], -sh);
            M = Mnew;
            int dn = Mlp - M; dn = dn > 0 ? 0 : dn;
            const float sA = ldexpf(1.0f, dn);
            const float sAx = lane0 ? 0.0f : sA;
            const int s0 = t0 & 31;

            // ---- 8 steps ----
#pragma unroll
            for (int u = 0; u < 8; ++u) {
                const uint4 row = cur[u];
                logs += __uint_as_float(row.z);
                unsigned p0 = __builtin_amdgcn_perm(row.y, row.x, ctrl);
                const half2_t h = __builtin_bit_cast(half2_t, p0);

                const float iv = __uint_as_float(comp4(icur[u >> 2], u & 3));
                const int   im = (int)comp4(icur[2 + (u >> 2)], u & 3);
                const float cf = ldexpf(iv, im - M);   // im <= M (squash)
                const float cfx = lane0 ? cf : 0.0f;
                const float Flr = shl1w_f(F[1]);       // lane n <- n-1
                const float fin = fmaf(Flr, sAx, cfx);

                F[1] = fmaf(F[0], (float)h.y, F[1]);
                F[0] = fmaf(fin,  (float)h.x, F[0]);

                // export boundary G_t[128(w+1)] = lane63's F[1], frame M
                const int es = (s0 + u + 1) & 31;
                if (lane63) { vexp[es] = F[1]; mexp[es] = M; }
            }
        }
        t0 += 8;
        asm volatile("s_waitcnt lgkmcnt(0)" ::: "memory");  // exports visible
        __builtin_amdgcn_s_barrier();
    };

#pragma unroll 1
    for (int c = 0; c < 65; ++c) {                 // 65*8 = 520 phases >= 518
        if (w == 0 && c < 64) {
            int cs = (c + 4 > 63) ? 63 : (c + 4);
            gload_lds16(gsrc + (size_t)(cs * 64 + l) * 64,
                        &ring[((c + 4) & 7) * 64 + l]);
            asm volatile("s_waitcnt vmcnt(3)" ::: "memory");
        }
#pragma unroll 1
        for (int pr = 0; pr < 4; ++pr) {
            phase(wA, wB, iA, iB);
            phase(wB, wA, iB, iA);
        }
    }

    // ---- epilogue: log2 reconstruction (denormal-safe) ----
    const float lgS = logs * 1.44269504088896341f; // log2(prod S)
#pragma unroll
    for (int i = 0; i < 2; ++i) {
        float v = fmaxf(F[i] * 16777216.0f, 1e-38f);
        garr[128 * w + 2 * l + 1 + i] = __log2f(v) - 24.0f + (float)M + lgS;
    }
    if (w == 0 && lane0) garr[0] = lgS;            // log2(G[0]) = 0
    __syncthreads();
    if (tid == 0) {
        const int sl = seqlens[b];
        out[b] = -(garr[sl] * LN2F) / (float)TT;
    }
}

extern "C" void kernel_launch(void* const* d_in, const int* in_sizes, int n_in,
                              void* d_out, int out_size, void* d_ws, size_t ws_size,
                              hipStream_t stream) {
    const float* x       = (const float*)d_in[0];
    const int*   seqs    = (const int*)d_in[1];
    const int*   seqlens = (const int*)d_in[2];
    float*       out     = (float*)d_out;
    uint4*       xq      = (uint4*)d_ws;           // TT*BB rows x 16 B = 4 MB

    ctc_prepass<<<(TT * BB) / 256, 256, 0, stream>>>(x, xq);
    ctc_scan<<<BB, 256, 0, stream>>>(xq, seqs, seqlens, out);
}

// Round 3
// 244.515 us; speedup vs baseline: 1.6178x; 1.6178x over previous
//
#include <hip/hip_runtime.h>
#include <hip/hip_fp16.h>

// CTC-like forward scan. R14 = R12 (single wave/CU, G-space) with the inner
// update forced to v_fma_mix_f32 via inline asm.
//   G_t[p] = G_{t-1}[p] + W_t[p] * G_{t-1}[p-1],  W = exp(x_i - x_4)
// R12 was issue-bound (VALUBusy 4.88 of 6.25 single-wave ceiling, ~50 VALU
// slots/step at 128.6 cy/step): the hoped-for fma_mix fusion did NOT happen,
// so each update paid extract+cvt+fma. Here each update is exactly one
// v_fma_mix_f32 consuming the f16 weight straight from the packed v_perm
// result (lo/hi via op_sel; op_sel_hi marks S1 as f16). Conversion inside
// fma_mix is exact -> numerics bit-identical to R12 (absmax 0.0).
// Step body: 4 v_perm + 8 v_fma_mix + 1 DPP + 1 fma + 1 add = 15 VALU.
// R13 (4-wave systolic) regressed 219->338: 520 barrier rounds + 4 waves
// bursting 12x ds_read_b128 through the single LDS pipe per CU = ~60% stall;
// reverted. Staging/bookkeeping/epilogue identical to R12: 8-row register
// windows, 4-chunk-ahead global_load_lds, renorm every 8 steps, down-only
// alignment, boundary via one v_mov_dpp wave_shr:1.

#define TT 4096
#define BB 64
#define PP 512
#define LN2F 0.69314718055994531f

__device__ __forceinline__ unsigned f16_bits(float f) {
    return (unsigned)__half_as_ushort(__float2half(f));   // v_cvt_f16_f32, RNE
}

// prepass: x[t][b][5] -> xq[t*64+b] = {f16W0|f16W1, f16W2|f16W3, f32 x4, 0}
__global__ __launch_bounds__(256, 1)
void ctc_prepass(const float* __restrict__ x, uint4* __restrict__ xq) {
    int j = blockIdx.x * 256 + threadIdx.x;        // j = t*64 + b
    const float* r = x + (size_t)j * 5;
    float x0 = r[0], x1 = r[1], x2 = r[2], x3 = r[3], x4 = r[4];
    float w0 = fminf(__expf(x0 - x4), 65000.0f);   // clamp: f16 inf insurance
    float w1 = fminf(__expf(x1 - x4), 65000.0f);
    float w2 = fminf(__expf(x2 - x4), 65000.0f);
    float w3 = fminf(__expf(x3 - x4), 65000.0f);
    uint4 o;
    o.x = f16_bits(w0) | (f16_bits(w1) << 16);
    o.y = f16_bits(w2) | (f16_bits(w3) << 16);
    o.z = __float_as_uint(x4);
    o.w = 0u;
    xq[j] = o;
}

__device__ __forceinline__ void gload_lds16(const void* g, void* l) {
    auto gp = (const __attribute__((address_space(1))) void*)(uintptr_t)g;
    auto lp = (__attribute__((address_space(3))) void*)(uintptr_t)l;
    __builtin_amdgcn_global_load_lds(gp, lp, 16, 0, 0);
}

// lane n <- lane n-1 across the whole wave; lane 0 keeps old (overridden).
__device__ __forceinline__ int shl1w_i(int s) {
    return __builtin_amdgcn_update_dpp(s, s, 0x138 /*wave_shr:1*/, 0xF, 0xF, false);
}
__device__ __forceinline__ float shl1w_f(float s) {
    return __int_as_float(shl1w_i(__float_as_int(s)));
}

// acc += s * f16(lo/hi of p)   -- one v_fma_mix_f32, f16 source in S1
#define FMA_MIX_LO(acc, s, p)                                              \
    asm("v_fma_mix_f32 %0, %1, %2, %0 op_sel:[0,0,0] op_sel_hi:[0,1,0]"    \
        : "+v"(acc) : "v"(s), "v"(p))
#define FMA_MIX_HI(acc, s, p)                                              \
    asm("v_fma_mix_f32 %0, %1, %2, %0 op_sel:[0,1,0] op_sel_hi:[0,1,0]"    \
        : "+v"(acc) : "v"(s), "v"(p))

__global__ __launch_bounds__(64, 1)
void ctc_scan(const uint4* __restrict__ xq, const int* __restrict__ seqs,
              const int* __restrict__ seqlens, float* __restrict__ out) {
    __shared__ __align__(16) uint4 ring[512];      // 8 KB: 8 chunks x 64 rows
    __shared__ float garr[PP + 1];

    const int b = blockIdx.x;
    const int l = threadIdx.x;                     // 0..63
    const bool lane0 = (l == 0);

    // per-lane v_perm byte controls (value i at bytes 2i,2i+1 of {row.y:row.x})
    unsigned ctrl[4];
#pragma unroll
    for (int k = 0; k < 4; ++k) {
        unsigned i0 = (unsigned)seqs[b * PP + 8 * l + 2 * k];
        unsigned i1 = (unsigned)seqs[b * PP + 8 * l + 2 * k + 1];
        ctrl[k] = (2 * i0) | ((2 * i0 + 1) << 8) | ((2 * i1) << 16) | ((2 * i1 + 1) << 24);
    }

    // xq row (t,b) at xq[t*64+b]; chunk c, lane l stages row t=c*64+l.
    const uint4* gsrc = xq + b;                    // + 64*t

    // ---- stage chunks 0..3 ----
#pragma unroll
    for (int c0 = 0; c0 < 4; ++c0)
        gload_lds16(gsrc + (size_t)(c0 * 64 + l) * 64, &ring[c0 * 64 + l]);
    asm volatile("s_waitcnt vmcnt(3)" ::: "memory");   // chunk 0 resident

    float F[8];                                    // G values, frame 2^M
#pragma unroll
    for (int i = 0; i < 8; ++i) F[i] = 0.0f;
    int M = 0;
    float logs = 0.0f;                             // sum of x_4 (nat log of prod S)

    uint4 wA[8], wB[8];
#pragma unroll
    for (int i = 0; i < 8; ++i) wA[i] = ring[i];   // window 0
    int nrow = 8;                                  // ring row of next window

    auto window = [&](uint4 (&cur)[8], uint4 (&nxt)[8]) {
        // ---- burst-load next window, pin above consumption ----
        const int rb = nrow & 511;
        nrow += 8;
#pragma unroll
        for (int i = 0; i < 8; ++i) nxt[i] = ring[rb + i];
        asm volatile("" ::: "memory");

        // ---- window bookkeeping: renorm + neighbor frame alignment ----
        float m = F[0];
#pragma unroll
        for (int i = 1; i < 8; ++i) m = fmaxf(m, F[i]);
        int e2 = ((__float_as_int(m) >> 23) & 0xFF) - 127;
        e2 = (m > 0.0f) ? e2 : 0;
        const int Mp = M + e2;                     // post-renorm frame
        const int Mlp = shl1w_i(Mp);               // neighbor's post-renorm frame
        // lane0's virtual left neighbor is G[0]=1 with frame 0
        int dl = (lane0 ? 0 : Mlp) - Mp;
        int dlc = dl > 0 ? dl : 0;                 // down-only self-squash
        const int Mnew = Mp + dlc;
        const int sh = Mnew - M;                   // >= 0
#pragma unroll
        for (int i = 0; i < 8; ++i) F[i] = ldexpf(F[i], -sh);
        M = Mnew;
        int dn = Mlp - M; dn = dn > 0 ? 0 : dn;
        const float sA   = ldexpf(1.0f, dn);       // neighbor -> my frame
        const float sAx  = lane0 ? 0.0f : sA;
        const float cfin = lane0 ? ldexpf(1.0f, -M) : 0.0f;  // G[0]=1 in my frame
        // (lane0: M >= 0 always -- pinned by dl = -Mp squash -- so no overflow)

        // ---- 8 steps: F[i] += Fs[i] * W[i]  (forced v_fma_mix_f32) ----
#pragma unroll
        for (int u = 0; u < 8; ++u) {
            const uint4 row = cur[u];
            logs += __uint_as_float(row.z);
            unsigned p0 = __builtin_amdgcn_perm(row.y, row.x, ctrl[0]);
            unsigned p1 = __builtin_amdgcn_perm(row.y, row.x, ctrl[1]);
            unsigned p2 = __builtin_amdgcn_perm(row.y, row.x, ctrl[2]);
            unsigned p3 = __builtin_amdgcn_perm(row.y, row.x, ctrl[3]);

            const float Flr = shl1w_f(F[7]);       // 1 DPP: lane n <- n-1
            const float fin = fmaf(Flr, sAx, cfin);

            FMA_MIX_HI(F[7], F[6], p3);            // F[7] += F[6] * W7
            FMA_MIX_LO(F[6], F[5], p3);            // F[6] += F[5] * W6
            FMA_MIX_HI(F[5], F[4], p2);
            FMA_MIX_LO(F[4], F[3], p2);
            FMA_MIX_HI(F[3], F[2], p1);
            FMA_MIX_LO(F[2], F[1], p1);
            FMA_MIX_HI(F[1], F[0], p0);
            FMA_MIX_LO(F[0], fin,  p0);
        }
    };

#pragma unroll 1
    for (int c = 0; c < 64; ++c) {
        int cs = (c + 4 > 63) ? 63 : (c + 4);
        gload_lds16(gsrc + (size_t)(cs * 64 + l) * 64, &ring[((c + 4) & 7) * 64 + l]);
        asm volatile("s_waitcnt vmcnt(3)" ::: "memory");   // chunk c+1 resident

#pragma unroll 1
        for (int pr = 0; pr < 4; ++pr) {
            window(wA, wB);
            window(wB, wA);
        }
    }

    // ---- epilogue: log2 reconstruction (denormal-safe) ----
    const float lgS = logs * 1.44269504088896341f;  // log2(prod S)
#pragma unroll
    for (int i = 0; i < 8; ++i) {
        float v = fmaxf(F[i] * 16777216.0f, 1e-38f);
        garr[8 * l + 1 + i] = __log2f(v) - 24.0f + (float)M + lgS;
    }
    if (lane0) garr[0] = lgS;                       // position 0: log2(1) + lgS
    __syncthreads();
    if (lane0) {
        const int sl = seqlens[b];
        out[b] = -(garr[sl] * LN2F) / (float)TT;
    }
}

extern "C" void kernel_launch(void* const* d_in, const int* in_sizes, int n_in,
                              void* d_out, int out_size, void* d_ws, size_t ws_size,
                              hipStream_t stream) {
    const float* x       = (const float*)d_in[0];
    const int*   seqs    = (const int*)d_in[1];
    const int*   seqlens = (const int*)d_in[2];
    float*       out     = (float*)d_out;
    uint4*       xq      = (uint4*)d_ws;           // TT*BB rows x 16 B = 4 MB

    ctc_prepass<<<(TT * BB) / 256, 256, 0, stream>>>(x, xq);
    ctc_scan<<<BB, 64, 0, stream>>>(xq, seqs, seqlens, out);
}